// Round 4
// baseline (902.918 us; speedup 1.0000x reference)
//
#include <hip/hip_runtime.h>
#include <hip/hip_bf16.h>
#include <stdint.h>

#define N_NODES 50000
#define N_EDGES 800000
#define IN_CH 256
#define HID 128
#define OUT_CH 64
#define EDGE_DIM 64

// agg_fused geometry: one block per 64-edge window of the dst-sorted edge list.
#define AGG_EW  64                   // base edge window per block
#define AGG_CAP 128                  // max edges touched (window + tail segment; maxdeg~45)
#define AGG_B   (N_EDGES / AGG_EW)   // 12500 (divides exactly)
#define SCB     196                  // scan blocks: ceil(N_NODES/256)

typedef __hip_bfloat16 bf16;
typedef __attribute__((ext_vector_type(8))) short short8;
typedef __attribute__((ext_vector_type(4))) float f32x4;

__device__ __forceinline__ void st_out(float* p, float v) { *p = v; }
__device__ __forceinline__ void st_out(bf16* p, float v) { *p = __float2bfloat16(v); }

// ---- one-shot weight prep: transpose + bf16 for all 5 weight matrices ----
__device__ __forceinline__ void wt_one(const float* W, bf16* Wt, int K, int N, int i) {
    int n = i % N, k = i / N;
    Wt[n * K + k] = __float2bfloat16(W[i]);
}
__launch_bounds__(256)
__global__ void wt_prep_all(const float* W_in, const float* W_e, const float* W1,
                            const float* W2, const float* W_out,
                            bf16* Wt_in, bf16* Wt_e, bf16* Wt_1, bf16* Wt_2, bf16* Wt_out) {
    int i = blockIdx.x * 256 + threadIdx.x;
    if (i < 32768)       wt_one(W_in,  Wt_in,  256, 128, i);
    else if (i < 40960)  wt_one(W_e,   Wt_e,    64, 128, i - 32768);
    else if (i < 57344)  wt_one(W1,    Wt_1,   128, 128, i - 40960);
    else if (i < 73728)  wt_one(W2,    Wt_2,   128, 128, i - 57344);
    else if (i < 81920)  wt_one(W_out, Wt_out, 128,  64, i - 73728);
}

// MFMA GEMM: out[r, c] = act( A[r,:] @ W[:,c] + b[c] )
template<int KTOT, int N, int MROWS, bool RELU, typename InT, typename OutT>
__launch_bounds__(256)
__global__ void gemm_mfma(const InT* __restrict__ A, const bf16* __restrict__ Wt,
                          const float* __restrict__ b, OutT* __restrict__ out, int M) {
    static_assert(KTOT % 64 == 0, "");
    constexpr int KC  = 64;
    constexpr int NCH = KTOT / KC;
    constexpr int KCP = KC + 8;            // 72: row = 144 B (16B-aligned, 2-way bank alias = free)
    constexpr int NT  = N / 16;
    constexpr int MT  = MROWS / 64;        // m-tiles per wave
    __shared__ __align__(16) bf16 Ws[N * KCP];
    __shared__ __align__(16) bf16 As[MROWS * KCP];

    const int tid  = threadIdx.x;
    const int wave = tid >> 6;
    const int lane = tid & 63;
    const int quad = lane >> 4;
    const int l16  = lane & 15;
    const int base = blockIdx.x * MROWS;

    f32x4 acc[MT][NT];
    #pragma unroll
    for (int m = 0; m < MT; m++)
        #pragma unroll
        for (int i = 0; i < NT; i++) acc[m][i] = (f32x4){0.f, 0.f, 0.f, 0.f};

    for (int ch = 0; ch < NCH; ch++) {
        const int kc = ch * KC;
        constexpr int WIT = N * KC / (256 * 8);
        #pragma unroll
        for (int it = 0; it < WIT; it++) {
            int t8 = (it * 256 + tid) * 8;
            int n = t8 / KC, k = t8 % KC;
            *(uint4*)&Ws[n * KCP + k] = *(const uint4*)&Wt[n * KTOT + kc + k];
        }
        if constexpr (sizeof(InT) == 4) {
            constexpr int AIT = MROWS * KC / (256 * 4);
            #pragma unroll
            for (int it = 0; it < AIT; it++) {
                int t4 = (it * 256 + tid) * 4;
                int r = t4 / KC, k = t4 % KC;
                int gr = base + r;
                float4 v = (gr < M) ? *(const float4*)&A[(size_t)gr * KTOT + kc + k]
                                    : make_float4(0.f, 0.f, 0.f, 0.f);
                *(__hip_bfloat162*)&As[r * KCP + k]     = __float22bfloat162_rn(make_float2(v.x, v.y));
                *(__hip_bfloat162*)&As[r * KCP + k + 2] = __float22bfloat162_rn(make_float2(v.z, v.w));
            }
        } else {
            constexpr int AIT = MROWS * KC / (256 * 8);
            #pragma unroll
            for (int it = 0; it < AIT; it++) {
                int t8 = (it * 256 + tid) * 8;
                int r = t8 / KC, k = t8 % KC;
                int gr = base + r;
                uint4 v = (gr < M) ? *(const uint4*)&A[(size_t)gr * KTOT + kc + k]
                                   : make_uint4(0u, 0u, 0u, 0u);
                *(uint4*)&As[r * KCP + k] = v;
            }
        }
        __syncthreads();

        #pragma unroll
        for (int ks = 0; ks < KC / 32; ks++) {
            short8 af[MT];
            #pragma unroll
            for (int m = 0; m < MT; m++)
                af[m] = *(const short8*)&As[(wave * MT * 16 + m * 16 + l16) * KCP + ks * 32 + quad * 8];
            #pragma unroll
            for (int nt = 0; nt < NT; nt++) {
                short8 bfr = *(const short8*)&Ws[(nt * 16 + l16) * KCP + ks * 32 + quad * 8];
                #pragma unroll
                for (int m = 0; m < MT; m++)
                    acc[m][nt] = __builtin_amdgcn_mfma_f32_16x16x32_bf16(af[m], bfr, acc[m][nt], 0, 0, 0);
            }
        }
        __syncthreads();
    }

    #pragma unroll
    for (int m = 0; m < MT; m++) {
        const int r0 = base + wave * MT * 16 + m * 16 + quad * 4;
        #pragma unroll
        for (int reg = 0; reg < 4; reg++) {
            int gr = r0 + reg;
            if (gr < M) {
                #pragma unroll
                for (int nt = 0; nt < NT; nt++) {
                    int col = nt * 16 + l16;
                    float v = acc[m][nt][reg] + b[col];
                    if (RELU) v = fmaxf(v, 0.f);
                    st_out(&out[(size_t)gr * N + col], v);
                }
            }
        }
    }
}

// ---- counting sort of edges by dst ----
__launch_bounds__(256)
__global__ void hist_kernel(const int* __restrict__ ei, int* __restrict__ counts) {
    int edge = blockIdx.x * 256 + threadIdx.x;
    if (edge < N_EDGES) atomicAdd(&counts[ei[N_EDGES + edge]], 1);
}

// ---- parallel two-level scan ----
__launch_bounds__(256)
__global__ void scan_a(const int* __restrict__ counts, int* __restrict__ bsum) {
    __shared__ int sh[256];
    const int tid = threadIdx.x;
    int n = blockIdx.x * 256 + tid;
    sh[tid] = (n < N_NODES) ? counts[n] : 0;
    __syncthreads();
    for (int off = 128; off > 0; off >>= 1) {
        if (tid < off) sh[tid] += sh[tid + off];
        __syncthreads();
    }
    if (tid == 0) bsum[blockIdx.x] = sh[0];
}

__launch_bounds__(256)
__global__ void scan_b(const int* __restrict__ bsum, int* __restrict__ bpre) {
    __shared__ int sh[256];
    const int tid = threadIdx.x;
    int v = (tid < SCB) ? bsum[tid] : 0;
    sh[tid] = v;
    __syncthreads();
    for (int off = 1; off < 256; off <<= 1) {
        int t = (tid >= off) ? sh[tid - off] : 0;
        __syncthreads();
        sh[tid] += t;
        __syncthreads();
    }
    if (tid < SCB) bpre[tid] = sh[tid] - v;   // exclusive
}

__launch_bounds__(256)
__global__ void scan_c(const int* __restrict__ counts, const int* __restrict__ bpre,
                       int* __restrict__ offsets, int* __restrict__ cursor) {
    __shared__ int sh[256];
    const int tid = threadIdx.x;
    int n = blockIdx.x * 256 + tid;
    int c = (n < N_NODES) ? counts[n] : 0;
    sh[tid] = c;
    __syncthreads();
    for (int off = 1; off < 256; off <<= 1) {
        int t = (tid >= off) ? sh[tid - off] : 0;
        __syncthreads();
        sh[tid] += t;
        __syncthreads();
    }
    if (n < N_NODES) {
        int excl = bpre[blockIdx.x] + sh[tid] - c;
        offsets[n] = excl;
        cursor[n]  = excl;
    }
    if (blockIdx.x == 0 && tid == 0) offsets[N_NODES] = N_EDGES;
}

// blkstart[b] = first node n with offsets[n] >= b*AGG_EW (disjoint writes, race-free)
__launch_bounds__(256)
__global__ void scan_d(const int* __restrict__ offsets, int* __restrict__ blkstart) {
    int n = blockIdx.x * 256 + threadIdx.x;
    if (n > N_NODES) return;
    int v = (n == N_NODES) ? N_EDGES : offsets[n];
    int lo = 0;
    if (n > 0) lo = offsets[n - 1] / AGG_EW + 1;
    int hi = v / AGG_EW;
    for (int bb = lo; bb <= hi; bb++) blkstart[bb] = n;
    if (n == N_NODES) blkstart[AGG_B + 1] = N_NODES;
}

// poe[edge] = sorted position; srcs[pos] = src node of edge at sorted pos
__launch_bounds__(256)
__global__ void scatter_perm(const int* __restrict__ ei, int* __restrict__ cursor,
                             int* __restrict__ poe, int* __restrict__ srcs) {
    int edge = blockIdx.x * 256 + threadIdx.x;
    if (edge >= N_EDGES) return;
    int dst = ei[N_EDGES + edge];
    int pos = atomicAdd(&cursor[dst], 1);
    poe[edge] = pos;
    srcs[pos] = ei[edge];
}

// eas[poe[edge]] = bf16(ea[edge])  — coalesced read, scattered 128-B row write
__launch_bounds__(256)
__global__ void ea_permute(const float* __restrict__ ea, const int* __restrict__ poe,
                           bf16* __restrict__ eas) {
    int t = blockIdx.x * 256 + threadIdx.x;
    int edge = t >> 4, l16 = t & 15;
    if (edge >= N_EDGES) return;
    float4 v = *(const float4*)&ea[(size_t)edge * EDGE_DIM + l16 * 4];
    int pos = poe[edge];
    __hip_bfloat162 p0 = __float22bfloat162_rn(make_float2(v.x, v.y));
    __hip_bfloat162 p1 = __float22bfloat162_rn(make_float2(v.z, v.w));
    uint2 u = make_uint2(*(uint32_t*)&p0, *(uint32_t*)&p1);
    *(uint2*)&eas[(size_t)pos * EDGE_DIM + l16 * 4] = u;
}

// ---- fused edge-projection + segmented aggregation ----
// z[n] = h[n] + sum_{pos in seg(n)} relu(h[srcs[pos]] + eas[pos] @ W_e + b_e)
__device__ __forceinline__ float blo(uint32_t u) { return __uint_as_float(u << 16); }
__device__ __forceinline__ float bhi(uint32_t u) { return __uint_as_float(u & 0xffff0000u); }

__launch_bounds__(256)
__global__ void agg_fused(const int* __restrict__ offsets, const int* __restrict__ blkstart,
                          const int* __restrict__ srcs, const bf16* __restrict__ eas,
                          const bf16* __restrict__ Wt_e, const float* __restrict__ b_e,
                          const bf16* __restrict__ h, bf16* __restrict__ z) {
    constexpr int P = 136;                         // et pitch (bf16), row = 272 B (16B-aligned)
    __shared__ __align__(16) bf16 et[AGG_CAP * P]; // 34.8 KB
    __shared__ int srcs_s[AGG_CAP + 4];            // +4 pad: phase-2 reads i+quad unmasked-safe

    const int b    = blockIdx.x;
    const int tid  = threadIdx.x;
    const int wave = tid >> 6;
    const int lane = tid & 63;
    const int quad = lane >> 4;
    const int l16  = lane & 15;

    const int n0 = blkstart[b], n1 = blkstart[b + 1];
    if (n0 >= n1) return;                          // uniform: safe before barriers
    const int e0 = offsets[n0];
    int e1 = offsets[n1];
    if (e1 > e0 + AGG_CAP) e1 = e0 + AGG_CAP;      // unreachable for maxdeg<64
    const int ne = e1 - e0;

    if (tid < AGG_CAP + 4) srcs_s[tid] = (tid < ne) ? srcs[e0 + tid] : 0;

    // ---- phase 1: e-tile = eas[e0..e1) @ W_e + b_e  (et[edge][ch] layout) ----
    // register double-buffer: prefetch subtile es+1 while computing es.
    short8 af[2][2];
    float4 bias[2];
    #pragma unroll
    for (int ct = 0; ct < 2; ct++) {
        int chr = (wave * 2 + ct) * 16 + l16;
        #pragma unroll
        for (int ks = 0; ks < 2; ks++)
            af[ct][ks] = *(const short8*)&Wt_e[chr * EDGE_DIM + ks * 32 + quad * 8];
        bias[ct] = *(const float4*)&b_e[(wave * 2 + ct) * 16 + quad * 4];
    }
    const int nsub = (ne + 15) >> 4;
    short8 cb0 = (short8){0,0,0,0,0,0,0,0}, cb1 = cb0;
    if (l16 < ne) {
        cb0 = *(const short8*)&eas[(size_t)(e0 + l16) * EDGE_DIM + quad * 8];
        cb1 = *(const short8*)&eas[(size_t)(e0 + l16) * EDGE_DIM + 32 + quad * 8];
    }
    for (int es = 0; es < nsub; es++) {
        short8 nb0 = (short8){0,0,0,0,0,0,0,0}, nb1 = nb0;
        int nrow = (es + 1) * 16 + l16;
        if (nrow < ne) {
            nb0 = *(const short8*)&eas[(size_t)(e0 + nrow) * EDGE_DIM + quad * 8];
            nb1 = *(const short8*)&eas[(size_t)(e0 + nrow) * EDGE_DIM + 32 + quad * 8];
        }
        #pragma unroll
        for (int ct = 0; ct < 2; ct++) {
            f32x4 acc = (f32x4){0.f, 0.f, 0.f, 0.f};
            acc = __builtin_amdgcn_mfma_f32_16x16x32_bf16(af[ct][0], cb0, acc, 0, 0, 0);
            acc = __builtin_amdgcn_mfma_f32_16x16x32_bf16(af[ct][1], cb1, acc, 0, 0, 0);
            int row = es * 16 + l16;                      // edge (col of D)
            int ch0 = (wave * 2 + ct) * 16 + quad * 4;    // channel (row of D)
            __hip_bfloat162 p0 = __float22bfloat162_rn(make_float2(acc[0] + bias[ct].x, acc[1] + bias[ct].y));
            __hip_bfloat162 p1 = __float22bfloat162_rn(make_float2(acc[2] + bias[ct].z, acc[3] + bias[ct].w));
            *(uint2*)&et[row * P + ch0] = make_uint2(*(uint32_t*)&p0, *(uint32_t*)&p1);
        }
        cb0 = nb0; cb1 = nb1;
    }
    __syncthreads();

    // ---- phase 2: segmented sum, 16 lanes/edge (8 ch/lane), 4 edges per step ----
    const int c8 = l16 * 8;
    for (int n = n0 + wave; n < n1; n += 4) {
        int s  = offsets[n] - e0;
        int ee = offsets[n + 1] - e0;
        if (ee > ne) ee = ne;
        float a[8];
        #pragma unroll
        for (int j = 0; j < 8; j++) a[j] = 0.f;
        for (int i = s; i < ee; i += 4) {
            int idx = i + quad;
            if (idx < ee) {
                int src = srcs_s[idx];
                uint4 hv = *(const uint4*)&h[(size_t)src * HID + c8];
                uint4 ev = *(const uint4*)&et[idx * P + c8];
                uint32_t hs[4] = {hv.x, hv.y, hv.z, hv.w};
                uint32_t vs[4] = {ev.x, ev.y, ev.z, ev.w};
                #pragma unroll
                for (int j = 0; j < 4; j++) {
                    a[2 * j]     += fmaxf(blo(hs[j]) + blo(vs[j]), 0.f);
                    a[2 * j + 1] += fmaxf(bhi(hs[j]) + bhi(vs[j]), 0.f);
                }
            }
        }
        // reduce across the 4 edge-groups (quads)
        #pragma unroll
        for (int j = 0; j < 8; j++) {
            a[j] += __shfl_xor(a[j], 16);
            a[j] += __shfl_xor(a[j], 32);
        }
        if (lane < 16) {
            uint4 hn = *(const uint4*)&h[(size_t)n * HID + c8];
            uint32_t hs[4] = {hn.x, hn.y, hn.z, hn.w};
            uint32_t o[4];
            #pragma unroll
            for (int j = 0; j < 4; j++) {
                __hip_bfloat162 p = __float22bfloat162_rn(
                    make_float2(a[2 * j] + blo(hs[j]), a[2 * j + 1] + bhi(hs[j])));
                o[j] = *(uint32_t*)&p;
            }
            *(uint4*)&z[(size_t)n * HID + c8] = make_uint4(o[0], o[1], o[2], o[3]);
        }
    }
}

extern "C" void kernel_launch(void* const* d_in, const int* in_sizes, int n_in,
                              void* d_out, int out_size, void* d_ws, size_t ws_size,
                              hipStream_t stream) {
    const float* x     = (const float*)d_in[0];
    const int*   ei    = (const int*)d_in[1];
    const float* ea    = (const float*)d_in[2];
    const float* W_in  = (const float*)d_in[3];
    const float* b_in  = (const float*)d_in[4];
    const float* W_e   = (const float*)d_in[5];
    const float* b_e   = (const float*)d_in[6];
    const float* W1    = (const float*)d_in[7];
    const float* b1    = (const float*)d_in[8];
    const float* W2    = (const float*)d_in[9];
    const float* b2    = (const float*)d_in[10];
    const float* W_out = (const float*)d_in[11];
    const float* b_out = (const float*)d_in[12];
    float* out = (float*)d_out;

    char* ws = (char*)d_ws;
    size_t off = 0;
    bf16*  h        = (bf16*) (ws + off); off += (size_t)N_NODES * HID * 2;      // 12.8 MB
    bf16*  z        = (bf16*) (ws + off); off += (size_t)N_NODES * HID * 2;      // 12.8 MB
    bf16*  eas      = (bf16*) (ws + off); off += (size_t)N_EDGES * EDGE_DIM * 2; // 102.4 MB
    int*   counts   = (int*)  (ws + off); off += (size_t)N_NODES * 4;
    int*   offsets  = (int*)  (ws + off); off += (size_t)(N_NODES + 1) * 4;
    int*   cursor   = (int*)  (ws + off); off += (size_t)N_NODES * 4;
    int*   poe      = (int*)  (ws + off); off += (size_t)N_EDGES * 4;
    int*   srcs     = (int*)  (ws + off); off += (size_t)N_EDGES * 4;
    int*   blkstart = (int*)  (ws + off); off += (size_t)(AGG_B + 2) * 4;
    int*   bsum     = (int*)  (ws + off); off += (size_t)SCB * 4;
    int*   bpre     = (int*)  (ws + off); off += (size_t)SCB * 4;
    bf16*  Wt_in    = (bf16*) (ws + off); off += (size_t)HID * IN_CH * 2;
    bf16*  Wt_e     = (bf16*) (ws + off); off += (size_t)HID * EDGE_DIM * 2;
    bf16*  Wt_1     = (bf16*) (ws + off); off += (size_t)HID * HID * 2;
    bf16*  Wt_2     = (bf16*) (ws + off); off += (size_t)HID * HID * 2;
    bf16*  Wt_out   = (bf16*) (ws + off); off += (size_t)OUT_CH * HID * 2;

    // ---- weight prep (one kernel) ----
    wt_prep_all<<<(81920 + 255) / 256, 256, 0, stream>>>(
        W_in, W_e, W1, W2, W_out, Wt_in, Wt_e, Wt_1, Wt_2, Wt_out);

    // ---- counting sort by dst + block ownership table (parallel scan) ----
    hipMemsetAsync(counts, 0, (size_t)N_NODES * 4, stream);
    hist_kernel<<<(N_EDGES + 255) / 256, 256, 0, stream>>>(ei, counts);
    scan_a<<<SCB, 256, 0, stream>>>(counts, bsum);
    scan_b<<<1, 256, 0, stream>>>(bsum, bpre);
    scan_c<<<SCB, 256, 0, stream>>>(counts, bpre, offsets, cursor);
    scan_d<<<SCB, 256, 0, stream>>>(offsets, blkstart);
    scatter_perm<<<(N_EDGES + 255) / 256, 256, 0, stream>>>(ei, cursor, poe, srcs);

    // ---- eas = bf16(ea) permuted into sorted order ----
    ea_permute<<<(N_EDGES * 16 + 255) / 256, 256, 0, stream>>>(ea, poe, eas);

    // h = x @ W_in + b_in   (fp32 in, bf16 out)
    gemm_mfma<IN_CH, HID, 64, false, float, bf16>
        <<<(N_NODES + 63) / 64, 256, 0, stream>>>(x, Wt_in, b_in, h, N_NODES);

    for (int layer = 0; layer < 3; ++layer) {
        agg_fused<<<AGG_B + 1, 256, 0, stream>>>(offsets, blkstart, srcs, eas, Wt_e, b_e, h, z);
        gemm_mfma<HID, HID, 64, true, bf16, bf16>
            <<<(N_NODES + 63) / 64, 256, 0, stream>>>(z, Wt_1, b1, h, N_NODES);
        gemm_mfma<HID, HID, 64, true, bf16, bf16>
            <<<(N_NODES + 63) / 64, 256, 0, stream>>>(h, Wt_2, b2, z, N_NODES);
        bf16* t = h; h = z; z = t;   // next layer's h is g2's output
    }

    // out = h @ W_out + b_out (fp32 out)
    gemm_mfma<HID, OUT_CH, 64, false, bf16, float>
        <<<(N_NODES + 63) / 64, 256, 0, stream>>>(h, Wt_out, b_out, out, N_NODES);
}

// Round 5
// 862.213 us; speedup vs baseline: 1.0472x; 1.0472x over previous
//
#include <hip/hip_runtime.h>
#include <hip/hip_bf16.h>
#include <stdint.h>

#define N_NODES 50000
#define N_EDGES 800000
#define IN_CH 256
#define HID 128
#define OUT_CH 64
#define EDGE_DIM 64

// agg_fused geometry: one block per 64-edge window of the dst-sorted edge list.
#define AGG_EW  64                   // base edge window per block
#define AGG_CAP 128                  // max edges touched (window + tail segment; maxdeg~45)
#define AGG_B   (N_EDGES / AGG_EW)   // 12500 (divides exactly)
#define SCB     196                  // scan blocks: ceil(N_NODES/256)

typedef __hip_bfloat16 bf16;
typedef __attribute__((ext_vector_type(8))) short short8;
typedef __attribute__((ext_vector_type(4))) float f32x4;

__device__ __forceinline__ void st_out(float* p, float v) { *p = v; }
__device__ __forceinline__ void st_out(bf16* p, float v) { *p = __float2bfloat16(v); }

// ---- one-shot weight prep: transpose + bf16 for all 5 weight matrices ----
__device__ __forceinline__ void wt_one(const float* W, bf16* Wt, int K, int N, int i) {
    int n = i % N, k = i / N;
    Wt[n * K + k] = __float2bfloat16(W[i]);
}
__launch_bounds__(256)
__global__ void wt_prep_all(const float* W_in, const float* W_e, const float* W1,
                            const float* W2, const float* W_out,
                            bf16* Wt_in, bf16* Wt_e, bf16* Wt_1, bf16* Wt_2, bf16* Wt_out) {
    int i = blockIdx.x * 256 + threadIdx.x;
    if (i < 32768)       wt_one(W_in,  Wt_in,  256, 128, i);
    else if (i < 40960)  wt_one(W_e,   Wt_e,    64, 128, i - 32768);
    else if (i < 57344)  wt_one(W1,    Wt_1,   128, 128, i - 40960);
    else if (i < 73728)  wt_one(W2,    Wt_2,   128, 128, i - 57344);
    else if (i < 81920)  wt_one(W_out, Wt_out, 128,  64, i - 73728);
}

// MFMA GEMM: out[r, c] = act( A[r,:] @ W[:,c] + b[c] )
template<int KTOT, int N, int MROWS, bool RELU, typename InT, typename OutT>
__launch_bounds__(256)
__global__ void gemm_mfma(const InT* __restrict__ A, const bf16* __restrict__ Wt,
                          const float* __restrict__ b, OutT* __restrict__ out, int M) {
    static_assert(KTOT % 64 == 0, "");
    constexpr int KC  = 64;
    constexpr int NCH = KTOT / KC;
    constexpr int KCP = KC + 8;            // 72: row = 144 B (16B-aligned, 2-way bank alias = free)
    constexpr int NT  = N / 16;
    constexpr int MT  = MROWS / 64;        // m-tiles per wave
    __shared__ __align__(16) bf16 Ws[N * KCP];
    __shared__ __align__(16) bf16 As[MROWS * KCP];

    const int tid  = threadIdx.x;
    const int wave = tid >> 6;
    const int lane = tid & 63;
    const int quad = lane >> 4;
    const int l16  = lane & 15;
    const int base = blockIdx.x * MROWS;

    f32x4 acc[MT][NT];
    #pragma unroll
    for (int m = 0; m < MT; m++)
        #pragma unroll
        for (int i = 0; i < NT; i++) acc[m][i] = (f32x4){0.f, 0.f, 0.f, 0.f};

    for (int ch = 0; ch < NCH; ch++) {
        const int kc = ch * KC;
        constexpr int WIT = N * KC / (256 * 8);
        #pragma unroll
        for (int it = 0; it < WIT; it++) {
            int t8 = (it * 256 + tid) * 8;
            int n = t8 / KC, k = t8 % KC;
            *(uint4*)&Ws[n * KCP + k] = *(const uint4*)&Wt[n * KTOT + kc + k];
        }
        if constexpr (sizeof(InT) == 4) {
            constexpr int AIT = MROWS * KC / (256 * 4);
            #pragma unroll
            for (int it = 0; it < AIT; it++) {
                int t4 = (it * 256 + tid) * 4;
                int r = t4 / KC, k = t4 % KC;
                int gr = base + r;
                float4 v = (gr < M) ? *(const float4*)&A[(size_t)gr * KTOT + kc + k]
                                    : make_float4(0.f, 0.f, 0.f, 0.f);
                *(__hip_bfloat162*)&As[r * KCP + k]     = __float22bfloat162_rn(make_float2(v.x, v.y));
                *(__hip_bfloat162*)&As[r * KCP + k + 2] = __float22bfloat162_rn(make_float2(v.z, v.w));
            }
        } else {
            constexpr int AIT = MROWS * KC / (256 * 8);
            #pragma unroll
            for (int it = 0; it < AIT; it++) {
                int t8 = (it * 256 + tid) * 8;
                int r = t8 / KC, k = t8 % KC;
                int gr = base + r;
                uint4 v = (gr < M) ? *(const uint4*)&A[(size_t)gr * KTOT + kc + k]
                                   : make_uint4(0u, 0u, 0u, 0u);
                *(uint4*)&As[r * KCP + k] = v;
            }
        }
        __syncthreads();

        #pragma unroll
        for (int ks = 0; ks < KC / 32; ks++) {
            short8 af[MT];
            #pragma unroll
            for (int m = 0; m < MT; m++)
                af[m] = *(const short8*)&As[(wave * MT * 16 + m * 16 + l16) * KCP + ks * 32 + quad * 8];
            #pragma unroll
            for (int nt = 0; nt < NT; nt++) {
                short8 bfr = *(const short8*)&Ws[(nt * 16 + l16) * KCP + ks * 32 + quad * 8];
                #pragma unroll
                for (int m = 0; m < MT; m++)
                    acc[m][nt] = __builtin_amdgcn_mfma_f32_16x16x32_bf16(af[m], bfr, acc[m][nt], 0, 0, 0);
            }
        }
        __syncthreads();
    }

    #pragma unroll
    for (int m = 0; m < MT; m++) {
        const int r0 = base + wave * MT * 16 + m * 16 + quad * 4;
        #pragma unroll
        for (int reg = 0; reg < 4; reg++) {
            int gr = r0 + reg;
            if (gr < M) {
                #pragma unroll
                for (int nt = 0; nt < NT; nt++) {
                    int col = nt * 16 + l16;
                    float v = acc[m][nt][reg] + b[col];
                    if (RELU) v = fmaxf(v, 0.f);
                    st_out(&out[(size_t)gr * N + col], v);
                }
            }
        }
    }
}

// ---- counting sort of edges by dst ----
__launch_bounds__(256)
__global__ void hist_kernel(const int* __restrict__ ei, int* __restrict__ counts) {
    int edge = blockIdx.x * 256 + threadIdx.x;
    if (edge < N_EDGES) atomicAdd(&counts[ei[N_EDGES + edge]], 1);
}

// ---- parallel two-level scan ----
__launch_bounds__(256)
__global__ void scan_a(const int* __restrict__ counts, int* __restrict__ bsum) {
    __shared__ int sh[256];
    const int tid = threadIdx.x;
    int n = blockIdx.x * 256 + tid;
    sh[tid] = (n < N_NODES) ? counts[n] : 0;
    __syncthreads();
    for (int off = 128; off > 0; off >>= 1) {
        if (tid < off) sh[tid] += sh[tid + off];
        __syncthreads();
    }
    if (tid == 0) bsum[blockIdx.x] = sh[0];
}

__launch_bounds__(256)
__global__ void scan_b(const int* __restrict__ bsum, int* __restrict__ bpre) {
    __shared__ int sh[256];
    const int tid = threadIdx.x;
    int v = (tid < SCB) ? bsum[tid] : 0;
    sh[tid] = v;
    __syncthreads();
    for (int off = 1; off < 256; off <<= 1) {
        int t = (tid >= off) ? sh[tid - off] : 0;
        __syncthreads();
        sh[tid] += t;
        __syncthreads();
    }
    if (tid < SCB) bpre[tid] = sh[tid] - v;   // exclusive
}

__launch_bounds__(256)
__global__ void scan_c(const int* __restrict__ counts, const int* __restrict__ bpre,
                       int* __restrict__ offsets, int* __restrict__ cursor) {
    __shared__ int sh[256];
    const int tid = threadIdx.x;
    int n = blockIdx.x * 256 + tid;
    int c = (n < N_NODES) ? counts[n] : 0;
    sh[tid] = c;
    __syncthreads();
    for (int off = 1; off < 256; off <<= 1) {
        int t = (tid >= off) ? sh[tid - off] : 0;
        __syncthreads();
        sh[tid] += t;
        __syncthreads();
    }
    if (n < N_NODES) {
        int excl = bpre[blockIdx.x] + sh[tid] - c;
        offsets[n] = excl;
        cursor[n]  = excl;
    }
    if (blockIdx.x == 0 && tid == 0) offsets[N_NODES] = N_EDGES;
}

// blkstart[b] = first node n with offsets[n] >= b*AGG_EW (disjoint writes, race-free)
__launch_bounds__(256)
__global__ void scan_d(const int* __restrict__ offsets, int* __restrict__ blkstart) {
    int n = blockIdx.x * 256 + threadIdx.x;
    if (n > N_NODES) return;
    int v = (n == N_NODES) ? N_EDGES : offsets[n];
    int lo = 0;
    if (n > 0) lo = offsets[n - 1] / AGG_EW + 1;
    int hi = v / AGG_EW;
    for (int bb = lo; bb <= hi; bb++) blkstart[bb] = n;
    if (n == N_NODES) blkstart[AGG_B + 1] = N_NODES;
}

// blkmeta[b] = {n0, n1, e0, e1} — one-load block descriptor for agg_fused
__launch_bounds__(256)
__global__ void scan_e(const int* __restrict__ blkstart, const int* __restrict__ offsets,
                       int4* __restrict__ blkmeta) {
    int b = blockIdx.x * 256 + threadIdx.x;
    if (b > AGG_B) return;
    int n0 = blkstart[b], n1 = blkstart[b + 1];
    int e0 = offsets[n0];
    int e1 = offsets[n1];
    if (e1 > e0 + AGG_CAP) e1 = e0 + AGG_CAP;   // unreachable for maxdeg<64
    blkmeta[b] = make_int4(n0, n1, e0, e1);
}

// poe[edge] = sorted position; srcs[pos] = src node of edge at sorted pos
__launch_bounds__(256)
__global__ void scatter_perm(const int* __restrict__ ei, int* __restrict__ cursor,
                             int* __restrict__ poe, int* __restrict__ srcs) {
    int edge = blockIdx.x * 256 + threadIdx.x;
    if (edge >= N_EDGES) return;
    int dst = ei[N_EDGES + edge];
    int pos = atomicAdd(&cursor[dst], 1);
    poe[edge] = pos;
    srcs[pos] = ei[edge];
}

// eas[poe[edge]] = bf16(ea[edge])  — coalesced read, scattered 128-B row write
__launch_bounds__(256)
__global__ void ea_permute(const float* __restrict__ ea, const int* __restrict__ poe,
                           bf16* __restrict__ eas) {
    int t = blockIdx.x * 256 + threadIdx.x;
    int edge = t >> 4, l16 = t & 15;
    if (edge >= N_EDGES) return;
    float4 v = *(const float4*)&ea[(size_t)edge * EDGE_DIM + l16 * 4];
    int pos = poe[edge];
    __hip_bfloat162 p0 = __float22bfloat162_rn(make_float2(v.x, v.y));
    __hip_bfloat162 p1 = __float22bfloat162_rn(make_float2(v.z, v.w));
    uint2 u = make_uint2(*(uint32_t*)&p0, *(uint32_t*)&p1);
    *(uint2*)&eas[(size_t)pos * EDGE_DIM + l16 * 4] = u;
}

// ---- fused edge-projection + message + segmented aggregation ----
// z[n] = h[n] + sum_{pos in seg(n)} relu(h[srcs[pos]] + eas[pos] @ W_e + b_e)
// Phase 1: MFMA e-proj -> LDS et[edge][ch].
// Phase 2: edge-parallel m = relu(h_src + e), in-place in et (gathers issued at entry).
// Phase 3: per-node seg-sum, pure LDS.
__device__ __forceinline__ float blo(uint32_t u) { return __uint_as_float(u << 16); }
__device__ __forceinline__ float bhi(uint32_t u) { return __uint_as_float(u & 0xffff0000u); }

__launch_bounds__(256)
__global__ void agg_fused(const int* __restrict__ offsets, const int4* __restrict__ blkmeta,
                          const int* __restrict__ srcs, const bf16* __restrict__ eas,
                          const bf16* __restrict__ Wt_e, const float* __restrict__ b_e,
                          const bf16* __restrict__ h, bf16* __restrict__ z) {
    constexpr int P = 136;                         // et pitch (bf16), row = 272 B (16B-aligned)
    __shared__ __align__(16) bf16 et[AGG_CAP * P]; // 34.8 KB

    const int b    = blockIdx.x;
    const int tid  = threadIdx.x;
    const int wave = tid >> 6;
    const int lane = tid & 63;
    const int quad = lane >> 4;
    const int l16  = lane & 15;

    const int4 mt = blkmeta[b];
    const int n0 = mt.x, n1 = mt.y, e0 = mt.z, e1 = mt.w;
    if (n0 >= n1) return;                          // uniform: safe before barriers
    const int ne = e1 - e0;
    const int c8 = l16 * 8;

    // ---- entry: issue ALL phase-2 gathers (8 independent 1-KB wave-loads in flight) ----
    // edge slot assignment: idx = r*64 + wave*16 + j*4 + quad  (bijective over [0,128))
    int sv[2][4];
    #pragma unroll
    for (int r = 0; r < 2; r++)
        #pragma unroll
        for (int j = 0; j < 4; j++) {
            int pos = e0 + r * 64 + wave * 16 + j * 4 + quad;
            if (pos >= N_EDGES) pos = N_EDGES - 1;     // clamp: always a valid node id
            sv[r][j] = srcs[pos];
        }
    uint4 hv[2][4];
    #pragma unroll
    for (int r = 0; r < 2; r++)
        #pragma unroll
        for (int j = 0; j < 4; j++)
            hv[r][j] = *(const uint4*)&h[(size_t)sv[r][j] * HID + c8];

    // ---- phase 1: e-tile = eas[e0..e1) @ W_e + b_e  (et[edge][ch] layout) ----
    short8 af[2][2];
    float4 bias[2];
    #pragma unroll
    for (int ct = 0; ct < 2; ct++) {
        int chr = (wave * 2 + ct) * 16 + l16;
        #pragma unroll
        for (int ks = 0; ks < 2; ks++)
            af[ct][ks] = *(const short8*)&Wt_e[chr * EDGE_DIM + ks * 32 + quad * 8];
        bias[ct] = *(const float4*)&b_e[(wave * 2 + ct) * 16 + quad * 4];
    }
    const int nsub = (ne + 15) >> 4;
    short8 cb0 = (short8){0,0,0,0,0,0,0,0}, cb1 = cb0;
    if (l16 < ne) {
        cb0 = *(const short8*)&eas[(size_t)(e0 + l16) * EDGE_DIM + quad * 8];
        cb1 = *(const short8*)&eas[(size_t)(e0 + l16) * EDGE_DIM + 32 + quad * 8];
    }
    for (int es = 0; es < nsub; es++) {
        short8 nb0 = (short8){0,0,0,0,0,0,0,0}, nb1 = nb0;
        int nrow = (es + 1) * 16 + l16;
        if (nrow < ne) {
            nb0 = *(const short8*)&eas[(size_t)(e0 + nrow) * EDGE_DIM + quad * 8];
            nb1 = *(const short8*)&eas[(size_t)(e0 + nrow) * EDGE_DIM + 32 + quad * 8];
        }
        #pragma unroll
        for (int ct = 0; ct < 2; ct++) {
            f32x4 acc = (f32x4){0.f, 0.f, 0.f, 0.f};
            acc = __builtin_amdgcn_mfma_f32_16x16x32_bf16(af[ct][0], cb0, acc, 0, 0, 0);
            acc = __builtin_amdgcn_mfma_f32_16x16x32_bf16(af[ct][1], cb1, acc, 0, 0, 0);
            int row = es * 16 + l16;                      // edge (col of D)
            int ch0 = (wave * 2 + ct) * 16 + quad * 4;    // channel (row of D)
            __hip_bfloat162 p0 = __float22bfloat162_rn(make_float2(acc[0] + bias[ct].x, acc[1] + bias[ct].y));
            __hip_bfloat162 p1 = __float22bfloat162_rn(make_float2(acc[2] + bias[ct].z, acc[3] + bias[ct].w));
            *(uint2*)&et[row * P + ch0] = make_uint2(*(uint32_t*)&p0, *(uint32_t*)&p1);
        }
        cb0 = nb0; cb1 = nb1;
    }
    __syncthreads();

    // ---- phase 2: m = relu(h_src + e), in-place (exclusive 16-B slot per lane) ----
    #pragma unroll
    for (int r = 0; r < 2; r++)
        #pragma unroll
        for (int j = 0; j < 4; j++) {
            int idx = r * 64 + wave * 16 + j * 4 + quad;
            if (idx < ne) {
                uint4 ev = *(const uint4*)&et[idx * P + c8];
                uint32_t hs[4] = {hv[r][j].x, hv[r][j].y, hv[r][j].z, hv[r][j].w};
                uint32_t vs[4] = {ev.x, ev.y, ev.z, ev.w};
                uint32_t o[4];
                #pragma unroll
                for (int k = 0; k < 4; k++) {
                    float lo = fmaxf(blo(hs[k]) + blo(vs[k]), 0.f);
                    float hi = fmaxf(bhi(hs[k]) + bhi(vs[k]), 0.f);
                    __hip_bfloat162 p = __float22bfloat162_rn(make_float2(lo, hi));
                    o[k] = *(uint32_t*)&p;
                }
                *(uint4*)&et[idx * P + c8] = make_uint4(o[0], o[1], o[2], o[3]);
            }
        }
    __syncthreads();

    // ---- phase 3: per-node seg-sum of m from LDS + self term ----
    for (int n = n0 + wave; n < n1; n += 4) {
        int s  = offsets[n]     - e0;
        int ee = offsets[n + 1] - e0;
        if (ee > ne) ee = ne;
        uint4 hn = *(const uint4*)&h[(size_t)n * HID + c8];   // issue early (self term)
        float a[8];
        #pragma unroll
        for (int j = 0; j < 8; j++) a[j] = 0.f;
        for (int i = s; i < ee; i += 4) {
            int idx = i + quad;
            if (idx < ee) {
                uint4 mv = *(const uint4*)&et[idx * P + c8];
                uint32_t ms[4] = {mv.x, mv.y, mv.z, mv.w};
                #pragma unroll
                for (int j = 0; j < 4; j++) {
                    a[2 * j]     += blo(ms[j]);
                    a[2 * j + 1] += bhi(ms[j]);
                }
            }
        }
        #pragma unroll
        for (int j = 0; j < 8; j++) {
            a[j] += __shfl_xor(a[j], 16);
            a[j] += __shfl_xor(a[j], 32);
        }
        if (lane < 16) {
            uint32_t hs[4] = {hn.x, hn.y, hn.z, hn.w};
            uint32_t o[4];
            #pragma unroll
            for (int j = 0; j < 4; j++) {
                __hip_bfloat162 p = __float22bfloat162_rn(
                    make_float2(a[2 * j] + blo(hs[j]), a[2 * j + 1] + bhi(hs[j])));
                o[j] = *(uint32_t*)&p;
            }
            *(uint4*)&z[(size_t)n * HID + c8] = make_uint4(o[0], o[1], o[2], o[3]);
        }
    }
}

extern "C" void kernel_launch(void* const* d_in, const int* in_sizes, int n_in,
                              void* d_out, int out_size, void* d_ws, size_t ws_size,
                              hipStream_t stream) {
    const float* x     = (const float*)d_in[0];
    const int*   ei    = (const int*)d_in[1];
    const float* ea    = (const float*)d_in[2];
    const float* W_in  = (const float*)d_in[3];
    const float* b_in  = (const float*)d_in[4];
    const float* W_e   = (const float*)d_in[5];
    const float* b_e   = (const float*)d_in[6];
    const float* W1    = (const float*)d_in[7];
    const float* b1    = (const float*)d_in[8];
    const float* W2    = (const float*)d_in[9];
    const float* b2    = (const float*)d_in[10];
    const float* W_out = (const float*)d_in[11];
    const float* b_out = (const float*)d_in[12];
    float* out = (float*)d_out;

    char* ws = (char*)d_ws;
    size_t off = 0;
    bf16*  h        = (bf16*) (ws + off); off += (size_t)N_NODES * HID * 2;      // 12.8 MB
    bf16*  z        = (bf16*) (ws + off); off += (size_t)N_NODES * HID * 2;      // 12.8 MB
    bf16*  eas      = (bf16*) (ws + off); off += (size_t)N_EDGES * EDGE_DIM * 2; // 102.4 MB
    int*   counts   = (int*)  (ws + off); off += (size_t)N_NODES * 4;
    int*   offsets  = (int*)  (ws + off); off += (size_t)(N_NODES + 1) * 4;
    int*   cursor   = (int*)  (ws + off); off += (size_t)N_NODES * 4;
    int*   poe      = (int*)  (ws + off); off += (size_t)N_EDGES * 4;
    int*   srcs     = (int*)  (ws + off); off += (size_t)N_EDGES * 4;
    int*   blkstart = (int*)  (ws + off); off += (size_t)(AGG_B + 2) * 4;
    int*   bsum     = (int*)  (ws + off); off += (size_t)SCB * 4;
    int*   bpre     = (int*)  (ws + off); off += (size_t)SCB * 4;
    off = (off + 15) & ~(size_t)15;
    int4*  blkmeta  = (int4*) (ws + off); off += (size_t)(AGG_B + 1) * 16;
    bf16*  Wt_in    = (bf16*) (ws + off); off += (size_t)HID * IN_CH * 2;
    bf16*  Wt_e     = (bf16*) (ws + off); off += (size_t)HID * EDGE_DIM * 2;
    bf16*  Wt_1     = (bf16*) (ws + off); off += (size_t)HID * HID * 2;
    bf16*  Wt_2     = (bf16*) (ws + off); off += (size_t)HID * HID * 2;
    bf16*  Wt_out   = (bf16*) (ws + off); off += (size_t)OUT_CH * HID * 2;

    // ---- weight prep (one kernel) ----
    wt_prep_all<<<(81920 + 255) / 256, 256, 0, stream>>>(
        W_in, W_e, W1, W2, W_out, Wt_in, Wt_e, Wt_1, Wt_2, Wt_out);

    // ---- counting sort by dst + block ownership tables (parallel scan) ----
    hipMemsetAsync(counts, 0, (size_t)N_NODES * 4, stream);
    hist_kernel<<<(N_EDGES + 255) / 256, 256, 0, stream>>>(ei, counts);
    scan_a<<<SCB, 256, 0, stream>>>(counts, bsum);
    scan_b<<<1, 256, 0, stream>>>(bsum, bpre);
    scan_c<<<SCB, 256, 0, stream>>>(counts, bpre, offsets, cursor);
    scan_d<<<SCB, 256, 0, stream>>>(offsets, blkstart);
    scan_e<<<(AGG_B + 256) / 256, 256, 0, stream>>>(blkstart, offsets, blkmeta);
    scatter_perm<<<(N_EDGES + 255) / 256, 256, 0, stream>>>(ei, cursor, poe, srcs);

    // ---- eas = bf16(ea) permuted into sorted order ----
    ea_permute<<<(N_EDGES * 16 + 255) / 256, 256, 0, stream>>>(ea, poe, eas);

    // h = x @ W_in + b_in   (fp32 in, bf16 out)
    gemm_mfma<IN_CH, HID, 64, false, float, bf16>
        <<<(N_NODES + 63) / 64, 256, 0, stream>>>(x, Wt_in, b_in, h, N_NODES);

    for (int layer = 0; layer < 3; ++layer) {
        agg_fused<<<AGG_B + 1, 256, 0, stream>>>(offsets, blkmeta, srcs, eas, Wt_e, b_e, h, z);
        gemm_mfma<HID, HID, 64, true, bf16, bf16>
            <<<(N_NODES + 63) / 64, 256, 0, stream>>>(z, Wt_1, b1, h, N_NODES);
        gemm_mfma<HID, HID, 64, true, bf16, bf16>
            <<<(N_NODES + 63) / 64, 256, 0, stream>>>(h, Wt_2, b2, z, N_NODES);
        bf16* t = h; h = z; z = t;   // next layer's h is g2's output
    }

    // out = h @ W_out + b_out (fp32 out)
    gemm_mfma<HID, OUT_CH, 64, false, bf16, float>
        <<<(N_NODES + 63) / 64, 256, 0, stream>>>(h, Wt_out, b_out, out, N_NODES);
}